// Round 1
// baseline (33022.003 us; speedup 1.0000x reference)
//
#include <hip/hip_runtime.h>

// ---------------- problem constants ----------------
#define BB 16          // batch
#define SS 64          // seq
#define HH 512         // hidden
#define MR (BB*SS)     // 1024 rows of (b,s)
#define GN (4*HH)      // 2048 gate cols
#define NLAYER 4
#define OUTD 10

typedef float   floatx4  __attribute__((ext_vector_type(4)));
typedef __bf16  bf16x8   __attribute__((ext_vector_type(8)));
typedef unsigned short ushort8v __attribute__((ext_vector_type(8)));

#define MFMA_BF16(a,b,c) __builtin_amdgcn_mfma_f32_16x16x32_bf16((a),(b),(c),0,0,0)

static __device__ __forceinline__ unsigned short f2bf_rne(float f) {
  union { float f; unsigned u; } v; v.f = f;
  unsigned r = v.u + 0x7fffu + ((v.u >> 16) & 1u);
  return (unsigned short)(r >> 16);
}

// load 8 consecutive fp32 and round to a bf16x8 MFMA fragment
static __device__ __forceinline__ bf16x8 load_a8(const float* __restrict__ p) {
  float4 x0 = *(const float4*)p;
  float4 x1 = *(const float4*)(p + 4);
  union { ushort8v u; bf16x8 b; } c;
  c.u[0] = f2bf_rne(x0.x); c.u[1] = f2bf_rne(x0.y);
  c.u[2] = f2bf_rne(x0.z); c.u[3] = f2bf_rne(x0.w);
  c.u[4] = f2bf_rne(x1.x); c.u[5] = f2bf_rne(x1.y);
  c.u[6] = f2bf_rne(x1.z); c.u[7] = f2bf_rne(x1.w);
  return c.b;
}

static __device__ __forceinline__ float sigm(float x) {
  return 1.f / (1.f + __expf(-x));
}

// ---------------- utility kernels ----------------
__global__ void hrm_zero_f32(float* p, int n) {
  int i = blockIdx.x * 256 + threadIdx.x;
  if (i < n) p[i] = 0.f;
}
__global__ void hrm_zero_u16(unsigned short* p, int n) {
  int i = blockIdx.x * 256 + threadIdx.x;
  if (i < n) p[i] = 0;
}
__global__ void hrm_cvt_bf16(unsigned short* __restrict__ dst,
                             const float* __restrict__ src, int n) {
  int i = blockIdx.x * 256 + threadIdx.x;
  if (i < n) dst[i] = f2bf_rne(src[i]);
}

// ---------------- generic MFMA GEMM: C[M,N] = A[M,K] @ W[N,K]^T (+epilogue) ----
// grid = (ceil(N/64), M/16), block = 64 (1 wave). Wave tile 16(M) x 64(N).
__global__ __launch_bounds__(64) void hrm_gemm16(
    const float* __restrict__ A, const unsigned short* __restrict__ W,
    float* __restrict__ C, const float* __restrict__ bias0,
    const float* __restrict__ bias1, const float* __restrict__ res0,
    const float* __restrict__ res1, int N, int K, int relu)
{
  const int lane  = threadIdx.x;
  const int mrow  = lane & 15;       // A row within tile / W row within sub-tile
  const int kq    = lane >> 4;       // k-quad
  const int m_base = blockIdx.y << 4;
  const int n_base = blockIdx.x << 6;

  floatx4 acc[4] = {{0.f,0.f,0.f,0.f},{0.f,0.f,0.f,0.f},
                    {0.f,0.f,0.f,0.f},{0.f,0.f,0.f,0.f}};
  const float* ap = A + (size_t)(m_base + mrow) * K + kq * 8;
  const unsigned short* wp = W + (size_t)(n_base + mrow) * K + kq * 8;

  #pragma unroll 4
  for (int kt = 0; kt < K; kt += 32) {
    bf16x8 a = load_a8(ap + kt);
    #pragma unroll
    for (int sub = 0; sub < 4; ++sub) {
      bf16x8 b = *(const bf16x8*)(wp + (size_t)sub * 16 * K + kt);
      acc[sub] = MFMA_BF16(a, b, acc[sub]);
    }
  }
  // C/D layout: col = lane&15, row = (lane>>4)*4 + r  [verified m89/m91]
  #pragma unroll
  for (int sub = 0; sub < 4; ++sub) {
    int n = n_base + sub * 16 + mrow;
    if (n < N) {
      #pragma unroll
      for (int r = 0; r < 4; ++r) {
        int m = m_base + kq * 4 + r;
        size_t idx = (size_t)m * N + n;
        float v = acc[sub][r];
        if (bias0) v += bias0[n];
        if (bias1) v += bias1[n];
        if (res0)  v += res0[idx];
        if (res1)  v += res1[idx];
        if (relu)  v = fmaxf(v, 0.f);
        C[idx] = v;
      }
    }
  }
}

// ---------------- grid barrier (16 co-resident blocks) ----------------
static __device__ __forceinline__ void gbar(int* cnt, int* gen, int nblk) {
  __syncthreads();
  if (threadIdx.x == 0) {
    __threadfence();   // release this block's h-writes to agent scope
    int g = __hip_atomic_load(gen, __ATOMIC_RELAXED, __HIP_MEMORY_SCOPE_AGENT);
    int a = __hip_atomic_fetch_add(cnt, 1, __ATOMIC_ACQ_REL, __HIP_MEMORY_SCOPE_AGENT);
    if (a == nblk - 1) {
      __hip_atomic_store(cnt, 0, __ATOMIC_RELAXED, __HIP_MEMORY_SCOPE_AGENT);
      __hip_atomic_fetch_add(gen, 1, __ATOMIC_RELEASE, __HIP_MEMORY_SCOPE_AGENT);
    } else {
      int cur;
      do {
        cur = __hip_atomic_load(gen, __ATOMIC_ACQUIRE, __HIP_MEMORY_SCOPE_AGENT);
      } while (cur == g);
    }
    __threadfence();
  }
  __syncthreads();
}

// ---------------- LSTM recurrence for one layer ----------------
// G: (1024, 2048) precomputed x@Wih^T + bih + bhh, rows indexed b*64+t.
// Whh: (2048, 512) bf16. Y: (1024, 512) layer output. hbuf: 2 x (16x512) fp32.
// 16 blocks x 256 threads; block owns h-cols [bid*32, bid*32+32); wave w = gate w.
__global__ __launch_bounds__(256) void hrm_lstm_rec(
    const float* __restrict__ G, const unsigned short* __restrict__ Whh,
    float* __restrict__ Y, float* __restrict__ hbuf, int* __restrict__ bar)
{
  __shared__ float cst[BB][32];       // cell state slice, persistent over t
  __shared__ float gt[4][BB][32];     // recurrent gate contributions

  const int tid  = threadIdx.x;
  const int bid  = blockIdx.x;        // 0..15
  const int lane = tid & 63;
  const int w    = tid >> 6;          // gate index 0..3 (i,f,g,o)
  const int mrow = lane & 15;         // batch for A-frag / col within sub for B
  const int kq   = lane >> 4;

  for (int i = tid; i < BB * 32; i += 256) ((float*)cst)[i] = 0.f;

  // B rows for this wave: n = w*512 + bid*32 + {0..31}
  const unsigned short* wbase = Whh + ((size_t)(w * HH + bid * 32)) * HH;
  const unsigned short* w0 = wbase + (size_t)mrow * HH + kq * 8;
  const unsigned short* w1 = w0 + (size_t)16 * HH;

  for (int t = 0; t < SS; ++t) {
    const float* hprev = hbuf + (((t & 1) ^ 1) * BB * HH);
    float*       hcur  = hbuf + ((t & 1) * BB * HH);

    if (t > 0) {
      floatx4 a0 = {0.f,0.f,0.f,0.f}, a1 = {0.f,0.f,0.f,0.f};
      const float* hp = hprev + mrow * HH + kq * 8;
      #pragma unroll 4
      for (int kt = 0; kt < HH; kt += 32) {
        bf16x8 a = load_a8(hp + kt);
        a0 = MFMA_BF16(a, *(const bf16x8*)(w0 + kt), a0);
        a1 = MFMA_BF16(a, *(const bf16x8*)(w1 + kt), a1);
      }
      #pragma unroll
      for (int r = 0; r < 4; ++r) {
        gt[w][kq * 4 + r][mrow]      = a0[r];
        gt[w][kq * 4 + r][16 + mrow] = a1[r];
      }
    }
    __syncthreads();

    { // epilogue: 256 threads cover 16 batches x 32 cols (2 cols each)
      int b  = tid >> 4;
      int j0 = tid & 15;
      const float* gr = G + (size_t)(b * SS + t) * GN;
      #pragma unroll
      for (int q = 0; q < 2; ++q) {
        int jj = j0 + q * 16;
        int n  = bid * 32 + jj;
        float gi = gr[n], gf = gr[HH + n], gg = gr[2 * HH + n], go = gr[3 * HH + n];
        if (t > 0) {
          gi += gt[0][b][jj]; gf += gt[1][b][jj];
          gg += gt[2][b][jj]; go += gt[3][b][jj];
        }
        float ig = sigm(gi), fg = sigm(gf), gv = tanhf(gg), og = sigm(go);
        float c = fg * cst[b][jj] + ig * gv;
        cst[b][jj] = c;
        float h = og * tanhf(c);
        hcur[b * HH + n] = h;
        Y[(size_t)(b * SS + t) * HH + n] = h;
      }
    }
    if (t < SS - 1) gbar(bar, bar + 1, gridDim.x);
  }
}

// ---------------- LayerNorm over concat([low, high]) ----------------
__global__ __launch_bounds__(256) void hrm_ln(
    const float* __restrict__ low, const float* __restrict__ high,
    const float* __restrict__ g, const float* __restrict__ bta,
    float* __restrict__ out)
{
  __shared__ float sa[256], sb[256];
  const int row = blockIdx.x;   // 0..1023
  const int tid = threadIdx.x;
  float vals[4], s = 0.f, s2 = 0.f;
  #pragma unroll
  for (int i = 0; i < 4; ++i) {
    int c = tid + i * 256;
    float v = (c < HH) ? low[(size_t)row * HH + c]
                       : high[(size_t)row * HH + (c - HH)];
    vals[i] = v; s += v; s2 += v * v;
  }
  sa[tid] = s; sb[tid] = s2; __syncthreads();
  for (int off = 128; off > 0; off >>= 1) {
    if (tid < off) { sa[tid] += sa[tid + off]; sb[tid] += sb[tid + off]; }
    __syncthreads();
  }
  float mu  = sa[0] * (1.f / 1024.f);
  float var = sb[0] * (1.f / 1024.f) - mu * mu;
  float rstd = rsqrtf(var + 1e-5f);
  #pragma unroll
  for (int i = 0; i < 4; ++i) {
    int c = tid + i * 256;
    out[(size_t)row * 1024 + c] = (vals[i] - mu) * rstd * g[c] + bta[c];
  }
}

// ---------------- host orchestration ----------------
extern "C" void kernel_launch(void* const* d_in, const int* in_sizes, int n_in,
                              void* d_out, int out_size, void* d_ws, size_t ws_size,
                              hipStream_t stream) {
  const float* x        = (const float*)d_in[0];
  const float* Wp_in    = (const float*)d_in[1];
  const float* bp_in    = (const float*)d_in[2];
  const float* low_Wih  = (const float*)d_in[3];
  const float* low_Whh  = (const float*)d_in[4];
  const float* low_bih  = (const float*)d_in[5];
  const float* low_bhh  = (const float*)d_in[6];
  const float* high_Wih = (const float*)d_in[7];
  const float* high_Whh = (const float*)d_in[8];
  const float* high_bih = (const float*)d_in[9];
  const float* high_bhh = (const float*)d_in[10];
  const float* W_lowp   = (const float*)d_in[11];
  const float* W_highp  = (const float*)d_in[12];
  const float* ln_g     = (const float*)d_in[13];
  const float* ln_b     = (const float*)d_in[14];
  const float* W1       = (const float*)d_in[15];
  const float* b1       = (const float*)d_in[16];
  const float* W2       = (const float*)d_in[17];
  const float* b2       = (const float*)d_in[18];
  const float* W3       = (const float*)d_in[19];
  const float* b3       = (const float*)d_in[20];

  char* wsp = (char*)d_ws;
  size_t off = 0;
  auto alloc = [&](size_t bytes) -> void* {
    void* p = wsp + off;
    off += (bytes + 255) & ~(size_t)255;
    return p;
  };
  const size_t WSZ = (size_t)GN * HH;  // 2048*512 elems per layer matrix
  unsigned short* wp_b   = (unsigned short*)alloc(512u * 512u * 2);
  unsigned short* lwih_b = (unsigned short*)alloc(NLAYER * WSZ * 2);
  unsigned short* lwhh_b = (unsigned short*)alloc(NLAYER * WSZ * 2);
  unsigned short* hwih_b = (unsigned short*)alloc(NLAYER * WSZ * 2);
  unsigned short* hwhh_b = (unsigned short*)alloc(NLAYER * WSZ * 2);
  unsigned short* wlp_b  = (unsigned short*)alloc(512u * 512u * 2);
  unsigned short* whp_b  = (unsigned short*)alloc(512u * 512u * 2);
  unsigned short* w1_b   = (unsigned short*)alloc(512u * 1024u * 2);
  unsigned short* w2_b   = (unsigned short*)alloc(256u * 512u * 2);
  unsigned short* w3p_b  = (unsigned short*)alloc(64u * 256u * 2);   // padded to 64 rows

  float* emb   = (float*)alloc((size_t)MR * HH * 4);
  float* lowb  = (float*)alloc((size_t)MR * HH * 4);
  float* highb = (float*)alloc((size_t)MR * HH * 4);
  float* xa    = (float*)alloc((size_t)MR * HH * 4);
  float* xb    = (float*)alloc((size_t)MR * HH * 4);
  float* Gbuf  = (float*)alloc((size_t)MR * GN * 4);   // also reused as `normed` (4MB < 8MB)
  float* hbuf  = (float*)alloc(2u * BB * HH * 4);
  int*   bar   = (int*)alloc(256);

  auto cvt = [&](unsigned short* dst, const float* src, int n) {
    hrm_cvt_bf16<<<(n + 255) / 256, 256, 0, stream>>>(dst, src, n);
  };
  // weight conversions (ws is re-poisoned every call, so redo every call)
  cvt(wp_b,   Wp_in,    512 * 512);
  cvt(lwih_b, low_Wih,  (int)(NLAYER * WSZ));
  cvt(lwhh_b, low_Whh,  (int)(NLAYER * WSZ));
  cvt(hwih_b, high_Wih, (int)(NLAYER * WSZ));
  cvt(hwhh_b, high_Whh, (int)(NLAYER * WSZ));
  cvt(wlp_b,  W_lowp,   512 * 512);
  cvt(whp_b,  W_highp,  512 * 512);
  cvt(w1_b,   W1,       512 * 1024);
  cvt(w2_b,   W2,       256 * 512);
  hrm_zero_u16<<<(64 * 256 + 255) / 256, 256, 0, stream>>>(w3p_b, 64 * 256);
  cvt(w3p_b, W3, OUTD * 256);

  // zero-init state buffers + barrier (ws poisoned 0xAA each call)
  hrm_zero_f32<<<(MR * HH + 255) / 256, 256, 0, stream>>>(lowb,  MR * HH);
  hrm_zero_f32<<<(MR * HH + 255) / 256, 256, 0, stream>>>(highb, MR * HH);
  hrm_zero_f32<<<1, 256, 0, stream>>>((float*)bar, 64);

  // emb = x @ Wp_in^T + bp_in
  hrm_gemm16<<<dim3(HH / 64, MR / 16), 64, 0, stream>>>(
      x, wp_b, emb, bp_in, nullptr, nullptr, nullptr, HH, HH, 0);

  // 8 low + 2 high level steps; order per reference
  const int seq[10] = {0, 0, 0, 0, 1, 0, 0, 0, 0, 1};
  for (int si = 0; si < 10; ++si) {
    const bool hi = seq[si] != 0;
    float* target = hi ? highb : lowb;
    const float* first  = target;
    const float* second = hi ? lowb : highb;
    const unsigned short* proj = hi ? whp_b : wlp_b;
    const unsigned short* wih  = hi ? hwih_b : lwih_b;
    const unsigned short* whh  = hi ? hwhh_b : lwhh_b;
    const float* bih = hi ? high_bih : low_bih;
    const float* bhh = hi ? high_bhh : low_bhh;

    // combined = second @ Wproj^T + first + emb
    hrm_gemm16<<<dim3(HH / 64, MR / 16), 64, 0, stream>>>(
        second, proj, xa, nullptr, nullptr, first, emb, HH, HH, 0);

    float* X  = xa;
    float* Yb = xb;
    for (int l = 0; l < NLAYER; ++l) {
      // G = X @ Wih_l^T + bih_l + bhh_l
      hrm_gemm16<<<dim3(GN / 64, MR / 16), 64, 0, stream>>>(
          X, wih + (size_t)l * WSZ, Gbuf, bih + l * GN, bhh + l * GN,
          nullptr, nullptr, GN, HH, 0);
      float* Yout = (l == NLAYER - 1) ? target : Yb;
      hrm_lstm_rec<<<16, 256, 0, stream>>>(
          Gbuf, whh + (size_t)l * WSZ, Yout, hbuf, bar);
      Yb = X;
      X  = Yout;
    }
  }

  // LayerNorm(concat) -> MLP
  float* normed = Gbuf;
  hrm_ln<<<MR, 256, 0, stream>>>(lowb, highb, ln_g, ln_b, normed);
  hrm_gemm16<<<dim3(HH / 64, MR / 16), 64, 0, stream>>>(
      normed, w1_b, xa, b1, nullptr, nullptr, nullptr, HH, 2 * HH, 1);
  hrm_gemm16<<<dim3(256 / 64, MR / 16), 64, 0, stream>>>(
      xa, w2_b, xb, b2, nullptr, nullptr, nullptr, 256, HH, 1);
  hrm_gemm16<<<dim3(1, MR / 16), 64, 0, stream>>>(
      xb, w3p_b, (float*)d_out, b3, nullptr, nullptr, nullptr, OUTD, 256, 0);
  (void)in_sizes; (void)n_in; (void)out_size; (void)ws_size;
}

// Round 2
// 18994.225 us; speedup vs baseline: 1.7385x; 1.7385x over previous
//
#include <hip/hip_runtime.h>

// ---------------- problem constants ----------------
#define BB 16          // batch
#define SS 64          // seq
#define HH 512         // hidden
#define MR (BB*SS)     // 1024 rows of (b,s)
#define GN (4*HH)      // 2048 gate cols
#define NLAYER 4
#define OUTD 10

typedef float   floatx4  __attribute__((ext_vector_type(4)));
typedef __bf16  bf16x8   __attribute__((ext_vector_type(8)));
typedef unsigned short ushort8v __attribute__((ext_vector_type(8)));
typedef int     intx4    __attribute__((ext_vector_type(4)));

#define MFMA_BF16(a,b,c) __builtin_amdgcn_mfma_f32_16x16x32_bf16((a),(b),(c),0,0,0)

static __device__ __forceinline__ unsigned short f2bf_rne(float f) {
  union { float f; unsigned u; } v; v.f = f;
  unsigned r = v.u + 0x7fffu + ((v.u >> 16) & 1u);
  return (unsigned short)(r >> 16);
}

// load 8 consecutive fp32 and round to a bf16x8 MFMA fragment
static __device__ __forceinline__ bf16x8 load_a8(const float* __restrict__ p) {
  float4 x0 = *(const float4*)p;
  float4 x1 = *(const float4*)(p + 4);
  union { ushort8v u; bf16x8 b; } c;
  c.u[0] = f2bf_rne(x0.x); c.u[1] = f2bf_rne(x0.y);
  c.u[2] = f2bf_rne(x0.z); c.u[3] = f2bf_rne(x0.w);
  c.u[4] = f2bf_rne(x1.x); c.u[5] = f2bf_rne(x1.y);
  c.u[6] = f2bf_rne(x1.z); c.u[7] = f2bf_rne(x1.w);
  return c.b;
}

static __device__ __forceinline__ float sigm(float x) {
  return 1.f / (1.f + __expf(-x));
}

// device-coherent (bypass L1/L2, hit IF$ coherent point) 16B load / 2B store.
// Equivalent to relaxed agent-scope atomics but vectorized; avoids ALL
// buffer_wbl2/buffer_inv L2-wide operations that made the old barrier 12.5us.
static __device__ __forceinline__ intx4 coh_load16(const void* p) {
  intx4 r;
  asm volatile("global_load_dwordx4 %0, %1, off sc0 sc1"
               : "=v"(r) : "v"(p) : "memory");
  return r;
}
static __device__ __forceinline__ void coh_store_short(void* p, unsigned v) {
  asm volatile("global_store_short %0, %1, off sc0 sc1"
               :: "v"(p), "v"(v) : "memory");
}
static __device__ __forceinline__ void wait_vm0() {
  asm volatile("s_waitcnt vmcnt(0)" ::: "memory");
}

// ---------------- utility kernels ----------------
__global__ void hrm_zero_f32(float* p, int n) {
  int i = blockIdx.x * 256 + threadIdx.x;
  if (i < n) p[i] = 0.f;
}
__global__ void hrm_zero_u16(unsigned short* p, int n) {
  int i = blockIdx.x * 256 + threadIdx.x;
  if (i < n) p[i] = 0;
}
__global__ void hrm_cvt_bf16(unsigned short* __restrict__ dst,
                             const float* __restrict__ src, int n) {
  int i = blockIdx.x * 256 + threadIdx.x;
  if (i < n) dst[i] = f2bf_rne(src[i]);
}

// ---------------- generic MFMA GEMM: C[M,N] = A[M,K] @ W[N,K]^T (+epilogue) ----
// grid = (ceil(N/64), M/16), block = 64 (1 wave). Wave tile 16(M) x 64(N).
__global__ __launch_bounds__(64) void hrm_gemm16(
    const float* __restrict__ A, const unsigned short* __restrict__ W,
    float* __restrict__ C, const float* __restrict__ bias0,
    const float* __restrict__ bias1, const float* __restrict__ res0,
    const float* __restrict__ res1, int N, int K, int relu)
{
  const int lane  = threadIdx.x;
  const int mrow  = lane & 15;
  const int kq    = lane >> 4;
  const int m_base = blockIdx.y << 4;
  const int n_base = blockIdx.x << 6;

  floatx4 acc[4] = {{0.f,0.f,0.f,0.f},{0.f,0.f,0.f,0.f},
                    {0.f,0.f,0.f,0.f},{0.f,0.f,0.f,0.f}};
  const float* ap = A + (size_t)(m_base + mrow) * K + kq * 8;
  const unsigned short* wp = W + (size_t)(n_base + mrow) * K + kq * 8;

  #pragma unroll 4
  for (int kt = 0; kt < K; kt += 32) {
    bf16x8 a = load_a8(ap + kt);
    #pragma unroll
    for (int sub = 0; sub < 4; ++sub) {
      bf16x8 b = *(const bf16x8*)(wp + (size_t)sub * 16 * K + kt);
      acc[sub] = MFMA_BF16(a, b, acc[sub]);
    }
  }
  // C/D layout: col = lane&15, row = (lane>>4)*4 + r  [verified m89/m91]
  #pragma unroll
  for (int sub = 0; sub < 4; ++sub) {
    int n = n_base + sub * 16 + mrow;
    if (n < N) {
      #pragma unroll
      for (int r = 0; r < 4; ++r) {
        int m = m_base + kq * 4 + r;
        size_t idx = (size_t)m * N + n;
        float v = acc[sub][r];
        if (bias0) v += bias0[n];
        if (bias1) v += bias1[n];
        if (res0)  v += res0[idx];
        if (res1)  v += res1[idx];
        if (relu)  v = fmaxf(v, 0.f);
        C[idx] = v;
      }
    }
  }
}

// ---------------- LSTM recurrence for one layer ----------------
// G: (1024, 2048) precomputed x@Wih^T + bih + bhh, rows indexed b*64+t.
// Whh: (2048, 512) bf16. Y: (1024, 512) fp32 layer output.
// hbuf: 2 x (16 x 512) bf16, device-coherent double buffer.
// flags[16]: per-block progress, value = epoch*64 + t + 1 (monotone across
//            the call's 40 dispatches; zeroed once per call).
// 16 blocks x 256 threads; block owns h-cols [bid*32, bid*32+32); wave w = gate w.
__global__ __launch_bounds__(256) void hrm_lstm_rec(
    const float* __restrict__ G, const unsigned short* __restrict__ Whh,
    float* __restrict__ Y, unsigned short* __restrict__ hbuf,
    int* __restrict__ flags, int epoch)
{
  __shared__ float cst[BB][32];              // cell state slice (per-thread cells)
  __shared__ float gt[4][BB][32];            // recurrent gate contributions
  __shared__ unsigned short hs[BB][520];     // staged h_prev, +8 pad (row 1040B -> conflict-free b128)

  const int tid  = threadIdx.x;
  const int bid  = blockIdx.x;               // 0..15
  const int lane = tid & 63;
  const int w    = tid >> 6;                 // gate index 0..3 (i,f,g,o)
  const int mrow = lane & 15;
  const int kq   = lane >> 4;
  const int b    = tid >> 4;                 // epilogue batch
  const int j0   = tid & 15;                 // epilogue col base

  // per-thread cell-state cells (same thread writes/reads -> no sync needed)
  cst[b][j0] = 0.f; cst[b][j0 + 16] = 0.f;

  const int base = epoch * 64;
  // B rows for this wave: n = w*512 + bid*32 + {0..31}
  const unsigned short* wbase = Whh + ((size_t)(w * HH + bid * 32)) * HH;
  const unsigned short* w0 = wbase + (size_t)mrow * HH + kq * 8;
  const unsigned short* w1 = w0 + (size_t)16 * HH;

  for (int t = 0; t < SS; ++t) {
    const int hb_prev = ((t & 1) ^ 1) * (BB * HH);
    const int hb_cur  = (t & 1) * (BB * HH);

    // prefetch this step's G row into registers (independent of the poll)
    float gv[2][4];
    {
      const float* gr = G + (size_t)(b * SS + t) * GN;
      #pragma unroll
      for (int q = 0; q < 2; ++q) {
        int n = bid * 32 + j0 + q * 16;
        gv[q][0] = gr[n];          gv[q][1] = gr[HH + n];
        gv[q][2] = gr[2 * HH + n]; gv[q][3] = gr[3 * HH + n];
      }
    }

    if (t > 0) {
      // ---- wait until all 16 blocks have published h(t-1) ----
      if (tid == 0) {
        const int tgt = base + t;   // flag value after step t-1
        for (;;) {
          intx4 f0 = coh_load16(flags);
          intx4 f1 = coh_load16(flags + 4);
          intx4 f2 = coh_load16(flags + 8);
          intx4 f3 = coh_load16(flags + 12);
          wait_vm0();
          int m = f0[0];
          #pragma unroll
          for (int i = 1; i < 4; ++i) m = (f0[i] < m) ? f0[i] : m;
          #pragma unroll
          for (int i = 0; i < 4; ++i) m = (f1[i] < m) ? f1[i] : m;
          #pragma unroll
          for (int i = 0; i < 4; ++i) m = (f2[i] < m) ? f2[i] : m;
          #pragma unroll
          for (int i = 0; i < 4; ++i) m = (f3[i] < m) ? f3[i] : m;
          if (m >= tgt) break;
        }
      }
      __syncthreads();

      // ---- stage h(t-1) (16KB bf16) global -> LDS, coherent loads ----
      {
        const unsigned short* hb = hbuf + hb_prev;
        intx4 st[4];
        #pragma unroll
        for (int k = 0; k < 4; ++k) {
          const unsigned short* src = hb + (size_t)(tid + k * 256) * 8;
          st[k] = coh_load16(src);
        }
        wait_vm0();
        #pragma unroll
        for (int k = 0; k < 4; ++k) {
          int c = tid + k * 256;
          *(intx4*)&hs[c >> 6][(c & 63) * 8] = st[k];
        }
      }
      __syncthreads();

      // ---- recurrent gates: h(t-1) @ Whh^T slice ----
      floatx4 a0 = {0.f,0.f,0.f,0.f}, a1 = {0.f,0.f,0.f,0.f};
      const unsigned short* hr = &hs[mrow][kq * 8];
      #pragma unroll 4
      for (int kt = 0; kt < HH; kt += 32) {
        bf16x8 a = *(const bf16x8*)(hr + kt);
        a0 = MFMA_BF16(a, *(const bf16x8*)(w0 + kt), a0);
        a1 = MFMA_BF16(a, *(const bf16x8*)(w1 + kt), a1);
      }
      #pragma unroll
      for (int r = 0; r < 4; ++r) {
        gt[w][kq * 4 + r][mrow]      = a0[r];
        gt[w][kq * 4 + r][16 + mrow] = a1[r];
      }
      __syncthreads();
    }

    // ---- epilogue: 256 threads cover 16 batches x 32 cols (2 cols each) ----
    #pragma unroll
    for (int q = 0; q < 2; ++q) {
      int jj = j0 + q * 16;
      int n  = bid * 32 + jj;
      float gi = gv[q][0], gf = gv[q][1], gg = gv[q][2], go = gv[q][3];
      if (t > 0) {
        gi += gt[0][b][jj]; gf += gt[1][b][jj];
        gg += gt[2][b][jj]; go += gt[3][b][jj];
      }
      float ig = sigm(gi), fg = sigm(gf), gvv = tanhf(gg), og = sigm(go);
      float c = fg * cst[b][jj] + ig * gvv;
      cst[b][jj] = c;
      float h = og * tanhf(c);
      Y[(size_t)(b * SS + t) * HH + n] = h;
      if (t < SS - 1) {
        // publish h as bf16 (identical rounding to what the MFMA consumes)
        coh_store_short(hbuf + hb_cur + b * HH + n, (unsigned)f2bf_rne(h));
      }
    }
    wait_vm0();            // own wave's coherent stores acked at IF$
    __syncthreads();       // all waves' stores acked
    if (t < SS - 1 && tid == 0) {
      __hip_atomic_store(&flags[bid], base + t + 1,
                         __ATOMIC_RELAXED, __HIP_MEMORY_SCOPE_AGENT);
    }
  }
}

// ---------------- LayerNorm over concat([low, high]) ----------------
__global__ __launch_bounds__(256) void hrm_ln(
    const float* __restrict__ low, const float* __restrict__ high,
    const float* __restrict__ g, const float* __restrict__ bta,
    float* __restrict__ out)
{
  __shared__ float sa[256], sb[256];
  const int row = blockIdx.x;   // 0..1023
  const int tid = threadIdx.x;
  float vals[4], s = 0.f, s2 = 0.f;
  #pragma unroll
  for (int i = 0; i < 4; ++i) {
    int c = tid + i * 256;
    float v = (c < HH) ? low[(size_t)row * HH + c]
                       : high[(size_t)row * HH + (c - HH)];
    vals[i] = v; s += v; s2 += v * v;
  }
  sa[tid] = s; sb[tid] = s2; __syncthreads();
  for (int off = 128; off > 0; off >>= 1) {
    if (tid < off) { sa[tid] += sa[tid + off]; sb[tid] += sb[tid + off]; }
    __syncthreads();
  }
  float mu  = sa[0] * (1.f / 1024.f);
  float var = sb[0] * (1.f / 1024.f) - mu * mu;
  float rstd = rsqrtf(var + 1e-5f);
  #pragma unroll
  for (int i = 0; i < 4; ++i) {
    int c = tid + i * 256;
    out[(size_t)row * 1024 + c] = (vals[i] - mu) * rstd * g[c] + bta[c];
  }
}

// ---------------- host orchestration ----------------
extern "C" void kernel_launch(void* const* d_in, const int* in_sizes, int n_in,
                              void* d_out, int out_size, void* d_ws, size_t ws_size,
                              hipStream_t stream) {
  const float* x        = (const float*)d_in[0];
  const float* Wp_in    = (const float*)d_in[1];
  const float* bp_in    = (const float*)d_in[2];
  const float* low_Wih  = (const float*)d_in[3];
  const float* low_Whh  = (const float*)d_in[4];
  const float* low_bih  = (const float*)d_in[5];
  const float* low_bhh  = (const float*)d_in[6];
  const float* high_Wih = (const float*)d_in[7];
  const float* high_Whh = (const float*)d_in[8];
  const float* high_bih = (const float*)d_in[9];
  const float* high_bhh = (const float*)d_in[10];
  const float* W_lowp   = (const float*)d_in[11];
  const float* W_highp  = (const float*)d_in[12];
  const float* ln_g     = (const float*)d_in[13];
  const float* ln_b     = (const float*)d_in[14];
  const float* W1       = (const float*)d_in[15];
  const float* b1       = (const float*)d_in[16];
  const float* W2       = (const float*)d_in[17];
  const float* b2       = (const float*)d_in[18];
  const float* W3       = (const float*)d_in[19];
  const float* b3       = (const float*)d_in[20];

  char* wsp = (char*)d_ws;
  size_t off = 0;
  auto alloc = [&](size_t bytes) -> void* {
    void* p = wsp + off;
    off += (bytes + 255) & ~(size_t)255;
    return p;
  };
  const size_t WSZ = (size_t)GN * HH;  // 2048*512 elems per layer matrix
  unsigned short* wp_b   = (unsigned short*)alloc(512u * 512u * 2);
  unsigned short* lwih_b = (unsigned short*)alloc(NLAYER * WSZ * 2);
  unsigned short* lwhh_b = (unsigned short*)alloc(NLAYER * WSZ * 2);
  unsigned short* hwih_b = (unsigned short*)alloc(NLAYER * WSZ * 2);
  unsigned short* hwhh_b = (unsigned short*)alloc(NLAYER * WSZ * 2);
  unsigned short* wlp_b  = (unsigned short*)alloc(512u * 512u * 2);
  unsigned short* whp_b  = (unsigned short*)alloc(512u * 512u * 2);
  unsigned short* w1_b   = (unsigned short*)alloc(512u * 1024u * 2);
  unsigned short* w2_b   = (unsigned short*)alloc(256u * 512u * 2);
  unsigned short* w3p_b  = (unsigned short*)alloc(64u * 256u * 2);   // padded to 64 rows

  float* emb   = (float*)alloc((size_t)MR * HH * 4);
  float* lowb  = (float*)alloc((size_t)MR * HH * 4);
  float* highb = (float*)alloc((size_t)MR * HH * 4);
  float* xa    = (float*)alloc((size_t)MR * HH * 4);
  float* xb    = (float*)alloc((size_t)MR * HH * 4);
  float* Gbuf  = (float*)alloc((size_t)MR * GN * 4);   // also reused as `normed`
  unsigned short* hbuf = (unsigned short*)alloc(2u * BB * HH * 2);
  int*   flags = (int*)alloc(256);

  auto cvt = [&](unsigned short* dst, const float* src, int n) {
    hrm_cvt_bf16<<<(n + 255) / 256, 256, 0, stream>>>(dst, src, n);
  };
  cvt(wp_b,   Wp_in,    512 * 512);
  cvt(lwih_b, low_Wih,  (int)(NLAYER * WSZ));
  cvt(lwhh_b, low_Whh,  (int)(NLAYER * WSZ));
  cvt(hwih_b, high_Wih, (int)(NLAYER * WSZ));
  cvt(hwhh_b, high_Whh, (int)(NLAYER * WSZ));
  cvt(wlp_b,  W_lowp,   512 * 512);
  cvt(whp_b,  W_highp,  512 * 512);
  cvt(w1_b,   W1,       512 * 1024);
  cvt(w2_b,   W2,       256 * 512);
  hrm_zero_u16<<<(64 * 256 + 255) / 256, 256, 0, stream>>>(w3p_b, 64 * 256);
  cvt(w3p_b, W3, OUTD * 256);

  // zero-init state buffers + flags (ws poisoned 0xAA each call)
  hrm_zero_f32<<<(MR * HH + 255) / 256, 256, 0, stream>>>(lowb,  MR * HH);
  hrm_zero_f32<<<(MR * HH + 255) / 256, 256, 0, stream>>>(highb, MR * HH);
  hrm_zero_f32<<<1, 256, 0, stream>>>((float*)flags, 64);

  // emb = x @ Wp_in^T + bp_in
  hrm_gemm16<<<dim3(HH / 64, MR / 16), 64, 0, stream>>>(
      x, wp_b, emb, bp_in, nullptr, nullptr, nullptr, HH, HH, 0);

  int epoch = 0;
  const int seq[10] = {0, 0, 0, 0, 1, 0, 0, 0, 0, 1};
  for (int si = 0; si < 10; ++si) {
    const bool hi = seq[si] != 0;
    float* target = hi ? highb : lowb;
    const float* first  = target;
    const float* second = hi ? lowb : highb;
    const unsigned short* proj = hi ? whp_b : wlp_b;
    const unsigned short* wih  = hi ? hwih_b : lwih_b;
    const unsigned short* whh  = hi ? hwhh_b : lwhh_b;
    const float* bih = hi ? high_bih : low_bih;
    const float* bhh = hi ? high_bhh : low_bhh;

    // combined = second @ Wproj^T + first + emb
    hrm_gemm16<<<dim3(HH / 64, MR / 16), 64, 0, stream>>>(
        second, proj, xa, nullptr, nullptr, first, emb, HH, HH, 0);

    float* X  = xa;
    float* Yb = xb;
    for (int l = 0; l < NLAYER; ++l) {
      // G = X @ Wih_l^T + bih_l + bhh_l
      hrm_gemm16<<<dim3(GN / 64, MR / 16), 64, 0, stream>>>(
          X, wih + (size_t)l * WSZ, Gbuf, bih + l * GN, bhh + l * GN,
          nullptr, nullptr, GN, HH, 0);
      float* Yout = (l == NLAYER - 1) ? target : Yb;
      ++epoch;
      hrm_lstm_rec<<<16, 256, 0, stream>>>(
          Gbuf, whh + (size_t)l * WSZ, Yout, hbuf, flags, epoch);
      Yb = X;
      X  = Yout;
    }
  }

  // LayerNorm(concat) -> MLP
  float* normed = Gbuf;
  hrm_ln<<<MR, 256, 0, stream>>>(lowb, highb, ln_g, ln_b, normed);
  hrm_gemm16<<<dim3(HH / 64, MR / 16), 64, 0, stream>>>(
      normed, w1_b, xa, b1, nullptr, nullptr, nullptr, HH, 2 * HH, 1);
  hrm_gemm16<<<dim3(256 / 64, MR / 16), 64, 0, stream>>>(
      xa, w2_b, xb, b2, nullptr, nullptr, nullptr, 256, HH, 1);
  hrm_gemm16<<<dim3(1, MR / 16), 64, 0, stream>>>(
      xb, w3p_b, (float*)d_out, b3, nullptr, nullptr, nullptr, OUTD, 256, 0);
  (void)in_sizes; (void)n_in; (void)out_size; (void)ws_size;
}